// Round 8
// baseline (99.474 us; speedup 1.0000x reference)
//
#include <hip/hip_runtime.h>

// Trilinear interpolation over a 256^3 f32 grid. Round 8:
//  - 1024 anisotropic bins of 16x32x32 cells; halo region 17x33x33 = 74KB LDS
//    -> 2 interp blocks resident per CU (stage of next bin overlaps processing
//    of current one; round 7 was serialized at 1 block/CU with 143.7KB).
//  - hist+scan ELIMINATED: capacity-padded buckets (cap ~8192 >> mean 1953),
//    cursor[b] = b*cap, single-pass block-aggregated scatter.
//  - scatter flush uses LDS-stored keys (no binary search).
//  - streaming out_sorted + final gather-permute (unchanged).

#define NBINS 1024            // 16 x 8 x 8 bins (x:16 cells, y:32, z:32)
#define SPTS 4096             // points per scatter block
#define SPPT 8                // points per thread (512-thread blocks)

#define RX 17                 // region x extent (16 + halo)
#define RYZ 1089              // 33*33
#define RN (RX * RYZ)         // 18513 floats = 74052 B

#define ITHREADS 1024         // interp block size (16 waves); 2 blocks/CU

__device__ __forceinline__ float interp_one(float ix, float iy, float iz,
                                            const float* __restrict__ g,
                                            bool& valid) {
    valid = (ix >= 0.0f) && (ix <= 255.0f) &&
            (iy >= 0.0f) && (iy <= 255.0f) &&
            (iz >= 0.0f) && (iz <= 255.0f);
    if (!valid) return 0.0f;

    float flx = floorf(ix), fcx = ceilf(ix);
    float fly = floorf(iy), fcy = ceilf(iy);
    float flz = floorf(iz), fcz = ceilf(iz);

    int x0 = (int)flx, x1 = (int)fcx;
    int y0 = (int)fly, y1 = (int)fcy;
    int z0 = (int)flz, z1 = (int)fcz;

    float wsx = ix - flx; if (wsx == 0.0f) wsx = 1.0f;
    float wux = fcx - ix; if (wux == 0.0f) wux = 1.0f;
    float wsy = iy - fly; if (wsy == 0.0f) wsy = 1.0f;
    float wuy = fcy - iy; if (wuy == 0.0f) wuy = 1.0f;
    float wsz = iz - flz; if (wsz == 0.0f) wsz = 1.0f;
    float wuz = fcz - iz; if (wuz == 0.0f) wuz = 1.0f;

    int bx0 = x0 << 16, bx1 = x1 << 16;
    int by0 = y0 << 8,  by1 = y1 << 8;

    float v0 = g[bx0 + by0 + z0];  float w0 = wux * wuy * wuz;
    float v1 = g[bx1 + by0 + z0];  float w1 = wsx * wuy * wuz;
    float v2 = g[bx0 + by1 + z0];  float w2 = wux * wsy * wuz;
    float v3 = g[bx1 + by1 + z0];  float w3 = wsx * wsy * wuz;
    float v4 = g[bx0 + by0 + z1];  float w4 = wux * wuy * wsz;
    float v5 = g[bx1 + by0 + z1];  float w5 = wsx * wuy * wsz;
    float v6 = g[bx0 + by1 + z1];  float w6 = wux * wsy * wsz;
    float v7 = g[bx1 + by1 + z1];  float w7 = wsx * wsy * wsz;

    float num = v0 * w0 + v1 * w1 + v2 * w2 + v3 * w3 +
                v4 * w4 + v5 * w5 + v6 * w6 + v7 * w7;
    float den = w0 + w1 + w2 + w3 + w4 + w5 + w6 + w7;
    return num / den;
}

// bins: x -> 16 cells (4-bit), y -> 32 cells (3-bit), z -> 32 cells (3-bit)
__device__ __forceinline__ unsigned bin_key(float ix, float iy, float iz) {
    ix = fminf(fmaxf(ix, 0.0f), 255.0f);
    iy = fminf(fmaxf(iy, 0.0f), 255.0f);
    iz = fminf(fmaxf(iz, 0.0f), 255.0f);
    int bx = ((int)ix) >> 4;
    int by = ((int)iy) >> 5;
    int bz = ((int)iz) >> 5;
    return (unsigned)((bx << 6) | (by << 3) | bz);   // 1024 bins
}

// ---------- fallback (round-1) kernel ----------
__global__ __launch_bounds__(256) void simplegrid_direct(
    const float* __restrict__ x, const float* __restrict__ grid,
    const float* __restrict__ lower, const float* __restrict__ res,
    float* __restrict__ out, int n)
{
    int i = blockIdx.x * blockDim.x + threadIdx.x;
    if (i >= n) return;
    float ix = (x[3 * i + 0] - lower[0]) / res[0];
    float iy = (x[3 * i + 1] - lower[1]) / res[1];
    float iz = (x[3 * i + 2] - lower[2]) / res[2];
    bool valid;
    float v = interp_one(ix, iy, iz, grid, valid);
    out[i] = valid ? v : 0.0f;
}

// ---------- bucketed pipeline ----------
__global__ __launch_bounds__(512) void init_cursor_kernel(
    unsigned* __restrict__ cursor, unsigned cap)
{
    int t = blockIdx.x * 512 + threadIdx.x;     // grid = 2 blocks
    if (t < NBINS) cursor[t] = (unsigned)t * cap;
}

__global__ __launch_bounds__(512) void scatter_kernel(
    const float* __restrict__ x, const float* __restrict__ lower,
    const float* __restrict__ res, unsigned* __restrict__ cursor,
    float* __restrict__ sx, float* __restrict__ sy, float* __restrict__ sz,
    unsigned* __restrict__ posbuf, int n)
{
    __shared__ float sxl[SPTS], syl[SPTS], szl[SPTS];       // 48 KB
    __shared__ unsigned short kyl[SPTS];                    // 8 KB
    __shared__ unsigned cnt[NBINS], pfx[NBINS], lcur[NBINS], gbase[NBINS]; // 16 KB
    __shared__ unsigned wsum[8];

    int t = threadIdx.x;
    int lane = t & 63, wave = t >> 6;
    cnt[2 * t] = 0u; cnt[2 * t + 1] = 0u;
    __syncthreads();

    float l0 = lower[0], l1 = lower[1], l2 = lower[2];
    float r0 = res[0],   r1 = res[1],   r2 = res[2];
    int base = blockIdx.x * SPTS;

    float px[SPPT], py[SPPT], pz[SPPT];
    unsigned key[SPPT];
    #pragma unroll
    for (int k = 0; k < SPPT; ++k) {
        int p = base + k * 512 + t;
        if (p < n) {
            px[k] = (x[3 * p + 0] - l0) / r0;
            py[k] = (x[3 * p + 1] - l1) / r1;
            pz[k] = (x[3 * p + 2] - l2) / r2;
            key[k] = bin_key(px[k], py[k], pz[k]);
            atomicAdd(&cnt[key[k]], 1u);
        }
    }
    __syncthreads();

    // exclusive prefix over 1024 bins: 2 bins per thread, wave scan + wsum
    unsigned c0 = cnt[2 * t], c1 = cnt[2 * t + 1];
    unsigned v = c0 + c1;
    unsigned s = v;
    #pragma unroll
    for (int off = 1; off < 64; off <<= 1) {
        unsigned u = __shfl_up(s, off);
        if (lane >= off) s += u;
    }
    if (lane == 63) wsum[wave] = s;
    __syncthreads();
    unsigned woff = 0, tot = 0;
    #pragma unroll
    for (int w = 0; w < 8; ++w) { if (w < wave) woff += wsum[w]; tot += wsum[w]; }
    unsigned excl = woff + s - v;
    pfx[2 * t] = excl;          lcur[2 * t] = excl;
    pfx[2 * t + 1] = excl + c0; lcur[2 * t + 1] = excl + c0;
    gbase[2 * t]     = c0 ? atomicAdd(&cursor[2 * t], c0) : 0u;
    gbase[2 * t + 1] = c1 ? atomicAdd(&cursor[2 * t + 1], c1) : 0u;
    __syncthreads();

    // placement into LDS (bin-sorted) + pos written directly (coalesced addr)
    #pragma unroll
    for (int k = 0; k < SPPT; ++k) {
        int p = base + k * 512 + t;
        if (p < n) {
            unsigned lp = atomicAdd(&lcur[key[k]], 1u);
            sxl[lp] = px[k]; syl[lp] = py[k]; szl[lp] = pz[k];
            kyl[lp] = (unsigned short)key[k];
            posbuf[p] = gbase[key[k]] + (lp - pfx[key[k]]);
        }
    }
    __syncthreads();

    // flush in sorted order -> contiguous per-bin runs
    for (unsigned q = t; q < tot; q += 512) {
        unsigned kk = kyl[q];
        unsigned dst = gbase[kk] + (q - pfx[kk]);
        sx[dst] = sxl[q];
        sy[dst] = syl[q];
        sz[dst] = szl[q];
    }
}

// One block per bin: stage 17x33x33 halo region (74KB) into LDS, gather from
// LDS. 1024 threads; 2 blocks/CU resident -> staging overlaps processing.
__global__ __launch_bounds__(ITHREADS) void interp_lds_kernel(
    const float* __restrict__ sx, const float* __restrict__ sy,
    const float* __restrict__ sz, const float* __restrict__ grid,
    const unsigned* __restrict__ cursor, float* __restrict__ osort,
    unsigned cap)
{
    extern __shared__ float lds[];
    int b = blockIdx.x;
    int t = threadIdx.x;
    int bx0 = (b >> 6) << 4;          // x base (16-cell bins)
    int by0 = ((b >> 3) & 7) << 5;    // y base (32-cell bins)
    int bz0 = (b & 7) << 5;           // z base (32-cell bins)

    // stage region: idx = lx*1089 + ly*33 + lz (z rows contiguous)
    for (int i = t; i < RN; i += ITHREADS) {
        int lx = i / RYZ;
        int r  = i - lx * RYZ;
        int ly = r / 33;
        int lz = r - ly * 33;
        int gx = bx0 + lx; if (gx > 255) gx = 255;
        int gy = by0 + ly; if (gy > 255) gy = 255;
        int gz = bz0 + lz; if (gz > 255) gz = 255;
        lds[i] = grid[(gx << 16) + (gy << 8) + gz];
    }
    __syncthreads();

    float fbx = (float)bx0, fby = (float)by0, fbz = (float)bz0;
    unsigned start = (unsigned)b * cap;
    unsigned end   = cursor[b];       // = start + bin count after scatter

    for (unsigned j = start + t; j < end; j += ITHREADS) {
        float ix = sx[j], iy = sy[j], iz = sz[j];
        bool valid = (ix >= 0.0f) && (ix <= 255.0f) &&
                     (iy >= 0.0f) && (iy <= 255.0f) &&
                     (iz >= 0.0f) && (iz <= 255.0f);
        float fx = fminf(fmaxf(ix, 0.0f), 255.0f) - fbx;
        float fy = fminf(fmaxf(iy, 0.0f), 255.0f) - fby;
        float fz = fminf(fmaxf(iz, 0.0f), 255.0f) - fbz;

        float flx = floorf(fx), fcx = ceilf(fx);
        float fly = floorf(fy), fcy = ceilf(fy);
        float flz = floorf(fz), fcz = ceilf(fz);
        int x0 = (int)flx, x1 = (int)fcx;
        int y0 = (int)fly, y1 = (int)fcy;
        int z0 = (int)flz, z1 = (int)fcz;

        float wsx = fx - flx; if (wsx == 0.0f) wsx = 1.0f;
        float wux = fcx - fx; if (wux == 0.0f) wux = 1.0f;
        float wsy = fy - fly; if (wsy == 0.0f) wsy = 1.0f;
        float wuy = fcy - fy; if (wuy == 0.0f) wuy = 1.0f;
        float wsz = fz - flz; if (wsz == 0.0f) wsz = 1.0f;
        float wuz = fcz - fz; if (wuz == 0.0f) wuz = 1.0f;

        int ax0 = x0 * RYZ, ax1 = x1 * RYZ;
        int ay0 = y0 * 33,  ay1 = y1 * 33;

        float v0 = lds[ax0 + ay0 + z0];  float w0 = wux * wuy * wuz;
        float v1 = lds[ax1 + ay0 + z0];  float w1 = wsx * wuy * wuz;
        float v2 = lds[ax0 + ay1 + z0];  float w2 = wux * wsy * wuz;
        float v3 = lds[ax1 + ay1 + z0];  float w3 = wsx * wsy * wuz;
        float v4 = lds[ax0 + ay0 + z1];  float w4 = wux * wuy * wsz;
        float v5 = lds[ax1 + ay0 + z1];  float w5 = wsx * wuy * wsz;
        float v6 = lds[ax0 + ay1 + z1];  float w6 = wux * wsy * wsz;
        float v7 = lds[ax1 + ay1 + z1];  float w7 = wsx * wsy * wsz;

        float num = v0 * w0 + v1 * w1 + v2 * w2 + v3 * w3 +
                    v4 * w4 + v5 * w5 + v6 * w6 + v7 * w7;
        float den = w0 + w1 + w2 + w3 + w4 + w5 + w6 + w7;
        osort[j] = valid ? (num / den) : 0.0f;
    }
}

__global__ __launch_bounds__(256) void permute_kernel(
    const float* __restrict__ out_sorted, const unsigned* __restrict__ pos,
    float* __restrict__ out, int n)
{
    int i = blockIdx.x * blockDim.x + threadIdx.x;
    if (i < n) out[i] = out_sorted[pos[i]];
}

extern "C" void kernel_launch(void* const* d_in, const int* in_sizes, int n_in,
                              void* d_out, int out_size, void* d_ws, size_t ws_size,
                              hipStream_t stream) {
    const float* x     = (const float*)d_in[0];
    const float* grid  = (const float*)d_in[1];
    const float* lower = (const float*)d_in[2];
    const float* res   = (const float*)d_in[3];
    float* out = (float*)d_out;

    int n = in_sizes[0] / 3;
    int blocks_pt = (n + 255) / 256;

    // capacity per bin: 4 cap-padded planes (sx,sy,sz,osort) + posbuf + ctrl
    size_t fixed = 4096 + (size_t)n * 4;                 // cursor + posbuf
    unsigned cap = 0;
    if (ws_size > fixed) {
        size_t c = (ws_size - fixed) / ((size_t)NBINS * 4 * 4);
        cap = (unsigned)(c > 8192 ? 8192 : c);
    }

    bool lds_ok = (hipFuncSetAttribute(
        (const void*)interp_lds_kernel,
        hipFuncAttributeMaxDynamicSharedMemorySize,
        RN * (int)sizeof(float)) == hipSuccess);

    // mean fill = n/1024 (~1953); require >= 2x mean + generous slack
    if (cap < 2560 || !lds_ok) {
        simplegrid_direct<<<blocks_pt, 256, 0, stream>>>(x, grid, lower, res, out, n);
        return;
    }

    size_t plane = (size_t)NBINS * cap * 4;
    char* ws = (char*)d_ws;
    unsigned* cursor = (unsigned*)(ws);
    float*    sx     = (float*)(ws + 4096);
    float*    sy     = (float*)(ws + 4096 + plane);
    float*    sz     = (float*)(ws + 4096 + 2 * plane);
    float*    osort  = (float*)(ws + 4096 + 3 * plane);
    unsigned* posbuf = (unsigned*)(ws + 4096 + 4 * plane);

    int blocks_sort = (n + SPTS - 1) / SPTS;

    init_cursor_kernel<<<2, 512, 0, stream>>>(cursor, cap);
    scatter_kernel<<<blocks_sort, 512, 0, stream>>>(
        x, lower, res, cursor, sx, sy, sz, posbuf, n);
    interp_lds_kernel<<<NBINS, ITHREADS, RN * sizeof(float), stream>>>(
        sx, sy, sz, grid, cursor, osort, cap);
    permute_kernel<<<blocks_pt, 256, 0, stream>>>(osort, posbuf, out, n);
}

// Round 9
// 84.527 us; speedup vs baseline: 1.1768x; 1.1768x over previous
//
#include <hip/hip_runtime.h>

// Trilinear interpolation over a 256^3 f32 grid. Round 9:
//  - 1024 anisotropic bins (16x32x32 cells); halo region 17x33x33 = 74KB LDS,
//    2 interp blocks/CU (round 8)
//  - capacity-padded buckets, no hist/scan (round 8)
//  - NEW: cursor is LINE-PADDED (1 u32 per 64B line) + reservation rotated per
//    block + issued before the scan -> kills the global-atomic line-contention
//    convoy that made scatter 51us
//  - NEW: payload packed into ONE interleaved plane p3[dst*3+c]: per-bin runs
//    are contiguous ~48B scattered stores (was 3 distant 4B planes)

#define NBINS 1024            // 16 x 8 x 8 bins (x:16 cells, y:32, z:32)
#define SPTS 4096             // points per scatter block
#define SPPT 8                // points per thread (512-thread blocks)

#define RX 17                 // region x extent (16 + halo)
#define RYZ 1089              // 33*33
#define RN (RX * RYZ)         // 18513 floats = 74052 B

#define ITHREADS 1024         // interp block size (16 waves); 2 blocks/CU
#define CSTRIDE 16            // cursor line-padding stride (u32 units)

__device__ __forceinline__ float interp_one(float ix, float iy, float iz,
                                            const float* __restrict__ g,
                                            bool& valid) {
    valid = (ix >= 0.0f) && (ix <= 255.0f) &&
            (iy >= 0.0f) && (iy <= 255.0f) &&
            (iz >= 0.0f) && (iz <= 255.0f);
    if (!valid) return 0.0f;

    float flx = floorf(ix), fcx = ceilf(ix);
    float fly = floorf(iy), fcy = ceilf(iy);
    float flz = floorf(iz), fcz = ceilf(iz);

    int x0 = (int)flx, x1 = (int)fcx;
    int y0 = (int)fly, y1 = (int)fcy;
    int z0 = (int)flz, z1 = (int)fcz;

    float wsx = ix - flx; if (wsx == 0.0f) wsx = 1.0f;
    float wux = fcx - ix; if (wux == 0.0f) wux = 1.0f;
    float wsy = iy - fly; if (wsy == 0.0f) wsy = 1.0f;
    float wuy = fcy - iy; if (wuy == 0.0f) wuy = 1.0f;
    float wsz = iz - flz; if (wsz == 0.0f) wsz = 1.0f;
    float wuz = fcz - iz; if (wuz == 0.0f) wuz = 1.0f;

    int bx0 = x0 << 16, bx1 = x1 << 16;
    int by0 = y0 << 8,  by1 = y1 << 8;

    float v0 = g[bx0 + by0 + z0];  float w0 = wux * wuy * wuz;
    float v1 = g[bx1 + by0 + z0];  float w1 = wsx * wuy * wuz;
    float v2 = g[bx0 + by1 + z0];  float w2 = wux * wsy * wuz;
    float v3 = g[bx1 + by1 + z0];  float w3 = wsx * wsy * wuz;
    float v4 = g[bx0 + by0 + z1];  float w4 = wux * wuy * wsz;
    float v5 = g[bx1 + by0 + z1];  float w5 = wsx * wuy * wsz;
    float v6 = g[bx0 + by1 + z1];  float w6 = wux * wsy * wsz;
    float v7 = g[bx1 + by1 + z1];  float w7 = wsx * wsy * wsz;

    float num = v0 * w0 + v1 * w1 + v2 * w2 + v3 * w3 +
                v4 * w4 + v5 * w5 + v6 * w6 + v7 * w7;
    float den = w0 + w1 + w2 + w3 + w4 + w5 + w6 + w7;
    return num / den;
}

// bins: x -> 16 cells (4-bit), y -> 32 cells (3-bit), z -> 32 cells (3-bit)
__device__ __forceinline__ unsigned bin_key(float ix, float iy, float iz) {
    ix = fminf(fmaxf(ix, 0.0f), 255.0f);
    iy = fminf(fmaxf(iy, 0.0f), 255.0f);
    iz = fminf(fmaxf(iz, 0.0f), 255.0f);
    int bx = ((int)ix) >> 4;
    int by = ((int)iy) >> 5;
    int bz = ((int)iz) >> 5;
    return (unsigned)((bx << 6) | (by << 3) | bz);   // 1024 bins
}

// ---------- fallback (round-1) kernel ----------
__global__ __launch_bounds__(256) void simplegrid_direct(
    const float* __restrict__ x, const float* __restrict__ grid,
    const float* __restrict__ lower, const float* __restrict__ res,
    float* __restrict__ out, int n)
{
    int i = blockIdx.x * blockDim.x + threadIdx.x;
    if (i >= n) return;
    float ix = (x[3 * i + 0] - lower[0]) / res[0];
    float iy = (x[3 * i + 1] - lower[1]) / res[1];
    float iz = (x[3 * i + 2] - lower[2]) / res[2];
    bool valid;
    float v = interp_one(ix, iy, iz, grid, valid);
    out[i] = valid ? v : 0.0f;
}

// ---------- bucketed pipeline ----------
__global__ __launch_bounds__(512) void init_cursor_kernel(
    unsigned* __restrict__ cursor, unsigned cap)
{
    int t = blockIdx.x * 512 + threadIdx.x;     // grid = 2 blocks
    if (t < NBINS) cursor[(size_t)t * CSTRIDE] = (unsigned)t * cap;
}

__global__ __launch_bounds__(512) void scatter_kernel(
    const float* __restrict__ x, const float* __restrict__ lower,
    const float* __restrict__ res, unsigned* __restrict__ cursor,
    float* __restrict__ p3, unsigned* __restrict__ posbuf, int n)
{
    __shared__ float sxl[SPTS], syl[SPTS], szl[SPTS];       // 48 KB
    __shared__ unsigned short kyl[SPTS];                    // 8 KB
    __shared__ unsigned cnt[NBINS], pfx[NBINS], lcur[NBINS], gbase[NBINS]; // 16 KB
    __shared__ unsigned wsum[8];

    int t = threadIdx.x;
    int lane = t & 63, wave = t >> 6;
    cnt[2 * t] = 0u; cnt[2 * t + 1] = 0u;
    __syncthreads();

    float l0 = lower[0], l1 = lower[1], l2 = lower[2];
    float r0 = res[0],   r1 = res[1],   r2 = res[2];
    int base = blockIdx.x * SPTS;

    float px[SPPT], py[SPPT], pz[SPPT];
    unsigned key[SPPT];
    #pragma unroll
    for (int k = 0; k < SPPT; ++k) {
        int p = base + k * 512 + t;
        if (p < n) {
            px[k] = (x[3 * p + 0] - l0) / r0;
            py[k] = (x[3 * p + 1] - l1) / r1;
            pz[k] = (x[3 * p + 2] - l2) / r2;
            key[k] = bin_key(px[k], py[k], pz[k]);
            atomicAdd(&cnt[key[k]], 1u);
        }
    }
    __syncthreads();

    // global reservation FIRST (rotated per block so concurrent blocks hit
    // different cursor lines), overlapped with the prefix scan below
    unsigned h = ((unsigned)blockIdx.x * 131u) & (NBINS - 1);
    unsigned b0 = (2u * t + h) & (NBINS - 1);
    unsigned b1 = (2u * t + 1u + h) & (NBINS - 1);
    unsigned cb0 = cnt[b0], cb1 = cnt[b1];
    if (cb0) gbase[b0] = atomicAdd(&cursor[(size_t)b0 * CSTRIDE], cb0);
    if (cb1) gbase[b1] = atomicAdd(&cursor[(size_t)b1 * CSTRIDE], cb1);

    // exclusive prefix over 1024 bins: 2 bins per thread, wave scan + wsum
    unsigned c0 = cnt[2 * t], c1 = cnt[2 * t + 1];
    unsigned v = c0 + c1;
    unsigned s = v;
    #pragma unroll
    for (int off = 1; off < 64; off <<= 1) {
        unsigned u = __shfl_up(s, off);
        if (lane >= off) s += u;
    }
    if (lane == 63) wsum[wave] = s;
    __syncthreads();
    unsigned woff = 0, tot = 0;
    #pragma unroll
    for (int w = 0; w < 8; ++w) { if (w < wave) woff += wsum[w]; tot += wsum[w]; }
    unsigned excl = woff + s - v;
    pfx[2 * t] = excl;          lcur[2 * t] = excl;
    pfx[2 * t + 1] = excl + c0; lcur[2 * t + 1] = excl + c0;
    __syncthreads();

    // placement into LDS (bin-sorted) + pos written directly (coalesced addr)
    #pragma unroll
    for (int k = 0; k < SPPT; ++k) {
        int p = base + k * 512 + t;
        if (p < n) {
            unsigned lp = atomicAdd(&lcur[key[k]], 1u);
            sxl[lp] = px[k]; syl[lp] = py[k]; szl[lp] = pz[k];
            kyl[lp] = (unsigned short)key[k];
            posbuf[p] = gbase[key[k]] + (lp - pfx[key[k]]);
        }
    }
    __syncthreads();

    // flush in sorted order -> contiguous 12B/pt runs in ONE plane
    for (unsigned q = t; q < tot; q += 512) {
        unsigned kk = kyl[q];
        unsigned dst = gbase[kk] + (q - pfx[kk]);
        size_t b3 = (size_t)dst * 3;
        p3[b3 + 0] = sxl[q];
        p3[b3 + 1] = syl[q];
        p3[b3 + 2] = szl[q];
    }
}

// One block per bin: stage 17x33x33 halo region (74KB) into LDS, gather from
// LDS. 1024 threads; 2 blocks/CU resident -> staging overlaps processing.
__global__ __launch_bounds__(ITHREADS) void interp_lds_kernel(
    const float* __restrict__ p3, const float* __restrict__ grid,
    const unsigned* __restrict__ cursor, float* __restrict__ osort,
    unsigned cap)
{
    extern __shared__ float lds[];
    int b = blockIdx.x;
    int t = threadIdx.x;
    int bx0 = (b >> 6) << 4;          // x base (16-cell bins)
    int by0 = ((b >> 3) & 7) << 5;    // y base (32-cell bins)
    int bz0 = (b & 7) << 5;           // z base (32-cell bins)

    // stage region: idx = lx*1089 + ly*33 + lz (z rows contiguous)
    for (int i = t; i < RN; i += ITHREADS) {
        int lx = i / RYZ;
        int r  = i - lx * RYZ;
        int ly = r / 33;
        int lz = r - ly * 33;
        int gx = bx0 + lx; if (gx > 255) gx = 255;
        int gy = by0 + ly; if (gy > 255) gy = 255;
        int gz = bz0 + lz; if (gz > 255) gz = 255;
        lds[i] = grid[(gx << 16) + (gy << 8) + gz];
    }
    __syncthreads();

    float fbx = (float)bx0, fby = (float)by0, fbz = (float)bz0;
    unsigned start = (unsigned)b * cap;
    unsigned end   = cursor[(size_t)b * CSTRIDE];   // start + bin count

    for (unsigned j = start + t; j < end; j += ITHREADS) {
        size_t b3 = (size_t)j * 3;
        float ix = p3[b3 + 0], iy = p3[b3 + 1], iz = p3[b3 + 2];
        bool valid = (ix >= 0.0f) && (ix <= 255.0f) &&
                     (iy >= 0.0f) && (iy <= 255.0f) &&
                     (iz >= 0.0f) && (iz <= 255.0f);
        float fx = fminf(fmaxf(ix, 0.0f), 255.0f) - fbx;
        float fy = fminf(fmaxf(iy, 0.0f), 255.0f) - fby;
        float fz = fminf(fmaxf(iz, 0.0f), 255.0f) - fbz;

        float flx = floorf(fx), fcx = ceilf(fx);
        float fly = floorf(fy), fcy = ceilf(fy);
        float flz = floorf(fz), fcz = ceilf(fz);
        int x0 = (int)flx, x1 = (int)fcx;
        int y0 = (int)fly, y1 = (int)fcy;
        int z0 = (int)flz, z1 = (int)fcz;

        float wsx = fx - flx; if (wsx == 0.0f) wsx = 1.0f;
        float wux = fcx - fx; if (wux == 0.0f) wux = 1.0f;
        float wsy = fy - fly; if (wsy == 0.0f) wsy = 1.0f;
        float wuy = fcy - fy; if (wuy == 0.0f) wuy = 1.0f;
        float wsz = fz - flz; if (wsz == 0.0f) wsz = 1.0f;
        float wuz = fcz - fz; if (wuz == 0.0f) wuz = 1.0f;

        int ax0 = x0 * RYZ, ax1 = x1 * RYZ;
        int ay0 = y0 * 33,  ay1 = y1 * 33;

        float v0 = lds[ax0 + ay0 + z0];  float w0 = wux * wuy * wuz;
        float v1 = lds[ax1 + ay0 + z0];  float w1 = wsx * wuy * wuz;
        float v2 = lds[ax0 + ay1 + z0];  float w2 = wux * wsy * wuz;
        float v3 = lds[ax1 + ay1 + z0];  float w3 = wsx * wsy * wuz;
        float v4 = lds[ax0 + ay0 + z1];  float w4 = wux * wuy * wsz;
        float v5 = lds[ax1 + ay0 + z1];  float w5 = wsx * wuy * wsz;
        float v6 = lds[ax0 + ay1 + z1];  float w6 = wux * wsy * wsz;
        float v7 = lds[ax1 + ay1 + z1];  float w7 = wsx * wsy * wsz;

        float num = v0 * w0 + v1 * w1 + v2 * w2 + v3 * w3 +
                    v4 * w4 + v5 * w5 + v6 * w6 + v7 * w7;
        float den = w0 + w1 + w2 + w3 + w4 + w5 + w6 + w7;
        osort[j] = valid ? (num / den) : 0.0f;
    }
}

__global__ __launch_bounds__(256) void permute_kernel(
    const float* __restrict__ out_sorted, const unsigned* __restrict__ pos,
    float* __restrict__ out, int n)
{
    int i = blockIdx.x * blockDim.x + threadIdx.x;
    if (i < n) out[i] = out_sorted[pos[i]];
}

extern "C" void kernel_launch(void* const* d_in, const int* in_sizes, int n_in,
                              void* d_out, int out_size, void* d_ws, size_t ws_size,
                              hipStream_t stream) {
    const float* x     = (const float*)d_in[0];
    const float* grid  = (const float*)d_in[1];
    const float* lower = (const float*)d_in[2];
    const float* res   = (const float*)d_in[3];
    float* out = (float*)d_out;

    int n = in_sizes[0] / 3;
    int blocks_pt = (n + 255) / 256;

    // ws: cursor (line-padded 64KB) + p3 (12B/slot) + osort (4B/slot) + posbuf
    size_t fixed = (size_t)NBINS * CSTRIDE * 4 + (size_t)n * 4;
    unsigned cap = 0;
    if (ws_size > fixed) {
        size_t c = (ws_size - fixed) / ((size_t)NBINS * 16);
        cap = (unsigned)(c > 8192 ? 8192 : c);
    }

    bool lds_ok = (hipFuncSetAttribute(
        (const void*)interp_lds_kernel,
        hipFuncAttributeMaxDynamicSharedMemorySize,
        RN * (int)sizeof(float)) == hipSuccess);

    // mean fill = n/1024 (~1953); require >= ~1.3x mean headroom minimum
    if (cap < 2560 || !lds_ok) {
        simplegrid_direct<<<blocks_pt, 256, 0, stream>>>(x, grid, lower, res, out, n);
        return;
    }

    char* ws = (char*)d_ws;
    size_t off_p3    = (size_t)NBINS * CSTRIDE * 4;        // 64 KB
    size_t off_osort = off_p3 + (size_t)NBINS * cap * 12;
    size_t off_pos   = off_osort + (size_t)NBINS * cap * 4;

    unsigned* cursor = (unsigned*)ws;
    float*    p3     = (float*)(ws + off_p3);
    float*    osort  = (float*)(ws + off_osort);
    unsigned* posbuf = (unsigned*)(ws + off_pos);

    int blocks_sort = (n + SPTS - 1) / SPTS;

    init_cursor_kernel<<<2, 512, 0, stream>>>(cursor, cap);
    scatter_kernel<<<blocks_sort, 512, 0, stream>>>(
        x, lower, res, cursor, p3, posbuf, n);
    interp_lds_kernel<<<NBINS, ITHREADS, RN * sizeof(float), stream>>>(
        p3, grid, cursor, osort, cap);
    permute_kernel<<<blocks_pt, 256, 0, stream>>>(osort, posbuf, out, n);
}